// Round 2
// baseline (79.184 us; speedup 1.0000x reference)
//
#include <hip/hip_runtime.h>
#include <hip/hip_bf16.h>

typedef __attribute__((ext_vector_type(8))) short short8;
typedef __attribute__((ext_vector_type(4))) float f32x4;

#define NQ 32      // queries
#define NM 32      // query tokens
#define NH 128     // head dim
#define ND 512     // docs
#define NN 180     // doc tokens
#define NNP 192    // padded doc tokens (12 tiles of 16)
#define LSTR 136   // LDS row stride in shorts (272 B, 16B-aligned rows, 2-way banks only)

static __device__ __forceinline__ unsigned short f2bf(float x) {
  __hip_bfloat16 h = __float2bfloat16(x);
  return __builtin_bit_cast(unsigned short, h);
}

// Qb = bf16(Q * q_mask), [32*32][128]
__global__ __launch_bounds__(256, 1) void prep_q_kernel(
    const float* __restrict__ Q, const int* __restrict__ qmask,
    unsigned short* __restrict__ Qb) {
  int idx = blockIdx.x * 256 + threadIdx.x;   // float4 index, 32768 total
  int row = idx >> 5;                          // qm row (32 float4 per row)
  float m = (float)qmask[row];
  float4 v = reinterpret_cast<const float4*>(Q)[idx];
  unsigned int lo = (unsigned)f2bf(v.x * m) | ((unsigned)f2bf(v.y * m) << 16);
  unsigned int hi = (unsigned)f2bf(v.z * m) | ((unsigned)f2bf(v.w * m) << 16);
  reinterpret_cast<uint2*>(Qb)[idx] = make_uint2(lo, hi);
}

// one workgroup per doc d; 4 waves; wave w owns n-tiles {3w, 3w+1, 3w+2} (48 B-frag regs)
// and loops over ALL 32 queries. Operands swapped: C[n_row, m_col] = mfma(D_frag, Q_frag)
// so max-over-n is a per-lane fold + 2 shuffles. Cross-wave combine via 16 KB LDS partials
// (aliased into the dead D-tile buffer after frag loads).
__global__ __launch_bounds__(256, 2) void maxsim_kernel(
    const float* __restrict__ D, const int* __restrict__ dmask,
    const unsigned short* __restrict__ Qb, float* __restrict__ out) {
  __shared__ unsigned short Dlds[NNP * LSTR];        // 52224 B
  float* part = reinterpret_cast<float*>(Dlds);      // [32 q][4 w][32 m] = 16 KB, aliased

  const int d = blockIdx.x;
  const int tid = threadIdx.x;
  const int lane = tid & 63;
  const int w = tid >> 6;
  const float NEG = -__builtin_inff();

  // ---- stage masked D -> LDS bf16 (coalesced float4 reads of the fp32 stream) ----
  const float4* Dsrc = reinterpret_cast<const float4*>(D) + d * (NN * NH / 4);
  for (int i = tid; i < NN * (NH / 4); i += 256) {
    int row = i >> 5;
    int c4 = i & 31;
    float m = (float)dmask[d * NN + row];
    float4 v = Dsrc[i];
    unsigned int lo = (unsigned)f2bf(v.x * m) | ((unsigned)f2bf(v.y * m) << 16);
    unsigned int hi = (unsigned)f2bf(v.z * m) | ((unsigned)f2bf(v.w * m) << 16);
    *reinterpret_cast<uint2*>(&Dlds[row * LSTR + c4 * 4]) = make_uint2(lo, hi);
  }
  for (int i = tid; i < (NNP - NN) * (NH / 4); i += 256) {  // zero pad rows 180..191
    int row = NN + (i >> 5);
    int c4 = i & 31;
    *reinterpret_cast<uint2*>(&Dlds[row * LSTR + c4 * 4]) = make_uint2(0u, 0u);
  }
  __syncthreads();

  const int bl = lane & 15;   // fragment row/col within tile
  const int bg = lane >> 4;   // k-group

  // ---- wave w loads its 3 n-tiles' fragments (D is the MFMA 'A' operand) ----
  short8 Da[3][4];
  #pragma unroll
  for (int i = 0; i < 3; ++i) {
    #pragma unroll
    for (int ks = 0; ks < 4; ++ks) {
      Da[i][ks] = *reinterpret_cast<const short8*>(
          &Dlds[((w * 3 + i) * 16 + bl) * LSTR + ks * 32 + bg * 8]);
    }
  }
  __syncthreads();   // Dlds dead from here; `part` region may be overwritten

  // ---- loop all 32 queries, no barriers ----
  for (int q = 0; q < NQ; ++q) {
    const unsigned short* Qp = Qb + q * (NM * NH);
    short8 Qf[2][4];
    #pragma unroll
    for (int mt = 0; mt < 2; ++mt) {
      #pragma unroll
      for (int ks = 0; ks < 4; ++ks) {
        Qf[mt][ks] = *reinterpret_cast<const short8*>(
            Qp + (mt * 16 + bl) * NH + ks * 32 + bg * 8);
      }
    }

    // 6 independent accumulator chains (3 nt x 2 mt), ks stepped outermost
    f32x4 acc[3][2];
    #pragma unroll
    for (int i = 0; i < 3; ++i)
      #pragma unroll
      for (int mt = 0; mt < 2; ++mt)
        acc[i][mt] = (f32x4){0.f, 0.f, 0.f, 0.f};

    #pragma unroll
    for (int ks = 0; ks < 4; ++ks)
      #pragma unroll
      for (int i = 0; i < 3; ++i)
        #pragma unroll
        for (int mt = 0; mt < 2; ++mt)
          acc[i][mt] = __builtin_amdgcn_mfma_f32_16x16x32_bf16(
              Da[i][ks], Qf[mt][ks], acc[i][mt], 0, 0, 0);

    // fold over this wave's n-tiles. C layout: col(m)=lane&15, n_local=bg*4+j.
    float run[2][4];
    #pragma unroll
    for (int mt = 0; mt < 2; ++mt)
      #pragma unroll
      for (int j = 0; j < 4; ++j) run[mt][j] = NEG;

    #pragma unroll
    for (int i = 0; i < 3; ++i) {
      const bool last = (w * 3 + i) == 11;   // tile 11: only n=176..179 (bg==0) real
      #pragma unroll
      for (int mt = 0; mt < 2; ++mt) {
        #pragma unroll
        for (int j = 0; j < 4; ++j) {
          float v = acc[i][mt][j];
          if (last && bg != 0) v = NEG;
          run[mt][j] = fmaxf(run[mt][j], v);
        }
      }
    }

    // reduce over j (4 n-rows) then over the 4 k-groups (lanes xor 16, 32)
    float r0 = fmaxf(fmaxf(run[0][0], run[0][1]), fmaxf(run[0][2], run[0][3]));
    float r1 = fmaxf(fmaxf(run[1][0], run[1][1]), fmaxf(run[1][2], run[1][3]));
    r0 = fmaxf(r0, __shfl_xor(r0, 16));
    r0 = fmaxf(r0, __shfl_xor(r0, 32));
    r1 = fmaxf(r1, __shfl_xor(r1, 16));
    r1 = fmaxf(r1, __shfl_xor(r1, 32));

    // lanes 0..31 write the wave's partial max for rows m=0..31 of this q
    if (lane < 32) {
      float v = (lane < 16) ? r0 : r1;   // m = lane
      part[(q * 4 + w) * 32 + lane] = v;
    }
  }
  __syncthreads();

  // ---- epilogue: max across 4 waves, sum over 32 m, one output per q ----
  {
    int q = tid >> 3;
    int g = tid & 7;
    float s = 0.f;
    #pragma unroll
    for (int k = 0; k < 4; ++k) {
      int m = g + 8 * k;
      float v = part[(q * 4 + 0) * 32 + m];
      v = fmaxf(v, part[(q * 4 + 1) * 32 + m]);
      v = fmaxf(v, part[(q * 4 + 2) * 32 + m]);
      v = fmaxf(v, part[(q * 4 + 3) * 32 + m]);
      s += v;
    }
    s += __shfl_xor(s, 1);
    s += __shfl_xor(s, 2);
    s += __shfl_xor(s, 4);
    if (g == 0) out[q * ND + d] = s;
  }
}

extern "C" void kernel_launch(void* const* d_in, const int* in_sizes, int n_in,
                              void* d_out, int out_size, void* d_ws, size_t ws_size,
                              hipStream_t stream) {
  const float* Q = (const float*)d_in[0];
  const float* D = (const float*)d_in[1];
  const int* qmask = (const int*)d_in[2];
  const int* dmask = (const int*)d_in[3];
  float* out = (float*)d_out;
  unsigned short* Qb = (unsigned short*)d_ws;  // 32*32*128 bf16 = 256 KB

  prep_q_kernel<<<(NQ * NM * NH / 4) / 256, 256, 0, stream>>>(Q, qmask, Qb);
  maxsim_kernel<<<ND, 256, 0, stream>>>(D, dmask, Qb, out);
}